// Round 2
// baseline (428.939 us; speedup 1.0000x reference)
//
#include <hip/hip_runtime.h>
#include <stdint.h>
#include <stddef.h>

// ============================================================================
// RegionAttn fused pipeline, bf16-MFMA GEMMs + fp32 small kernels.
// B=4096, C=19, D=256, H=8, DK=32, FF=1024.
// GEMM: C[M,N] = act(A[M,K] @ Wt[N,K]^T), all bf16, fp32 accum.
//
// Workspace map (MB offsets; X2-class buffers are 38MB EXACTLY = 77824*512B):
//   WT    @0    (2MB)   weights bf16, whole run
//   FE    @2    (8MB)   steps 2..6
//   Q4    @10   K4 @18  V4 @26  CTX4 @34  O4 @42   (8MB each, steps 3..6)
//   X2    @50   (38MB)  steps 6..10
//   Q19   @88   K19 @126  V19 @164  CTX19 @202    (38MB each, steps 7..9)
//   O19   @88   (alias Q19, dead after attn19)     steps 9..10
//   FUSED @126  (alias K19, dead)                  steps 10..12
//   H     @164  (76MB, alias V19+CTX19, dead)      step 11
//   F2    @50   (alias X2, dead after step 10)     steps 11..12
// Peak = 240MB.
// ============================================================================

#define DEVINL __device__ __forceinline__

typedef __attribute__((ext_vector_type(8))) short short8;
typedef __attribute__((ext_vector_type(4))) float floatx4;
typedef __attribute__((ext_vector_type(8))) unsigned short ushort8;
typedef __attribute__((ext_vector_type(4))) unsigned short ushort4v;

DEVINL float bf2f(unsigned short u){
  union { unsigned int i; float f; } x; x.i = ((unsigned int)u) << 16; return x.f;
}
DEVINL unsigned short f2bf(float f){
  union { float f; unsigned int i; } x; x.f = f;
  unsigned int r = x.i + 0x7fffu + ((x.i >> 16) & 1u);   // RNE
  return (unsigned short)(r >> 16);
}

typedef __attribute__((address_space(1))) void gvoid_t;
typedef __attribute__((address_space(3))) void lvoid_t;
DEVINL void gload_lds16(const void* g, void* l){
  // async global->LDS, 16B per lane; LDS dest = wave-uniform base + lane*16
  __builtin_amdgcn_global_load_lds((gvoid_t*)g, (lvoid_t*)l, 16, 0, 0);
}

// ---------------------------------------------------------------------------
// Weight prep: fp32 [K][N] -> bf16 transposed [N][K].
// Layout in wt (elements): 8 x 65536 (rq,rk,rv,ro,lq,lk,lv,lo), w1t @524288
// ([1024][256]), w2t @786432 ([256][1024]).  Total 1,048,576 elems (2MB).
// ---------------------------------------------------------------------------
__global__ __launch_bounds__(256) void wprep_all(
    const float* __restrict__ rq, const float* __restrict__ rk,
    const float* __restrict__ rv, const float* __restrict__ ro,
    const float* __restrict__ lq, const float* __restrict__ lk,
    const float* __restrict__ lv, const float* __restrict__ lo,
    const float* __restrict__ w1, const float* __restrict__ w2,
    unsigned short* __restrict__ wt)
{
  int idx = blockIdx.x * 256 + threadIdx.x;      // 0 .. 1048575
  const float* W; unsigned short* D; int N, r;
  const int K = (idx < 786432) ? 256 : 1024;
  if (idx < 524288){
    int wsel = idx >> 16; r = idx & 65535; N = 256; D = wt + wsel * 65536;
    switch (wsel){
      case 0: W = rq; break; case 1: W = rk; break; case 2: W = rv; break; case 3: W = ro; break;
      case 4: W = lq; break; case 5: W = lk; break; case 6: W = lv; break; default: W = lo; break;
    }
  } else if (idx < 786432){
    r = idx - 524288; N = 1024; D = wt + 524288; W = w1;
  } else {
    r = idx - 786432; N = 256; D = wt + 786432; W = w2;
  }
  int k = r / N, n = r - k * N;
  D[(size_t)n * K + k] = f2bf(W[r]);
}

// ---------------------------------------------------------------------------
// Region avg-pool: x fp32 [B,19,256] -> fe bf16 [B,4,256]
// ---------------------------------------------------------------------------
__global__ __launch_bounds__(256) void pool_kernel(const float* __restrict__ x,
                                                   unsigned short* __restrict__ fe)
{
  const int b = blockIdx.x, d = threadIdx.x;
  const float* xb = x + (size_t)b * 4864 + d;
  float s0 = xb[0*256]+xb[1*256]+xb[5*256]+xb[8*256]+xb[9*256]+xb[10*256]+xb[14*256];
  float s1 = xb[2*256]+xb[11*256]+xb[17*256];
  float s2 = xb[3*256]+xb[12*256]+xb[18*256];
  float s3 = xb[4*256]+xb[6*256]+xb[7*256]+xb[13*256]+xb[15*256]+xb[16*256];
  unsigned short* fb = fe + (size_t)b * 1024 + d;
  fb[0]   = f2bf(s0 * (1.f/7.f));
  fb[256] = f2bf(s1 * (1.f/3.f));
  fb[512] = f2bf(s2 * (1.f/3.f));
  fb[768] = f2bf(s3 * (1.f/6.f));
}

// ---------------------------------------------------------------------------
// GEMM: C[M,N] = act(A[M,K] @ Bt[N,K]^T). BM=BN=128, BK=64, 256 thr (4 waves).
// LDS: byte(row, kb) = row*128 + (kb ^ ((row&7)<<4))  (XOR swizzle, staged via
// global_load_lds with linear LDS dest + pre-swizzled global source).
// MFMA 16x16x32 bf16; identical (lane-half,e)->k map for A and B fragments.
// C/D: col=lane&15, row=(lane>>4)*4+reg  [HW-verified].
// ---------------------------------------------------------------------------
template<int RELU>
__global__ __launch_bounds__(256, 2)
void gemm_kernel(const unsigned short* __restrict__ A,
                 const unsigned short* __restrict__ Bt,
                 unsigned short* __restrict__ C, int M, int N, int K)
{
  __shared__ __align__(1024) unsigned short lds[2][2][8192];  // 64 KB
  const int tid  = threadIdx.x;
  const int wave = tid >> 6, lane = tid & 63;
  const int wm = wave >> 1, wn = wave & 1;
  const int rowA0 = blockIdx.x * 128;
  const int rowB0 = blockIdx.y * 128;
  const int stg_row = lane >> 3;                         // 0..7 in 8-row chunk
  const int stg_kb  = (((lane & 7) ^ (lane >> 3)) << 4); // pre-swizzled src kbyte

  floatx4 acc[4][4];
  #pragma unroll
  for (int i = 0; i < 4; ++i)
    #pragma unroll
    for (int j = 0; j < 4; ++j) acc[i][j] = (floatx4){0.f, 0.f, 0.f, 0.f};

  const int nk = K >> 6;
  int cur = 0;
  #pragma unroll
  for (int s = 0; s < 4; ++s){
    int chunk = wave * 4 + s;
    int r = chunk * 8 + stg_row;
    gload_lds16((const char*)(A  + (size_t)(rowA0 + r) * K) + stg_kb,
                (char*)(&lds[0][0][0]) + chunk * 1024);
    gload_lds16((const char*)(Bt + (size_t)(rowB0 + r) * K) + stg_kb,
                (char*)(&lds[0][1][0]) + chunk * 1024);
  }
  __syncthreads();

  for (int kt = 0; kt < nk; ++kt){
    if (kt + 1 < nk){
      const int kbase = (kt + 1) << 7;   // bytes
      #pragma unroll
      for (int s = 0; s < 4; ++s){
        int chunk = wave * 4 + s;
        int r = chunk * 8 + stg_row;
        gload_lds16((const char*)(A  + (size_t)(rowA0 + r) * K) + kbase + stg_kb,
                    (char*)(&lds[cur ^ 1][0][0]) + chunk * 1024);
        gload_lds16((const char*)(Bt + (size_t)(rowB0 + r) * K) + kbase + stg_kb,
                    (char*)(&lds[cur ^ 1][1][0]) + chunk * 1024);
      }
    }
    const char* As = (const char*)(&lds[cur][0][0]);
    const char* Bs = (const char*)(&lds[cur][1][0]);
    #pragma unroll
    for (int kk = 0; kk < 2; ++kk){
      short8 a[4], b[4];
      #pragma unroll
      for (int i = 0; i < 4; ++i){
        int row = wm * 64 + i * 16 + (lane & 15);
        int kb  = (kk * 64 + ((lane >> 4) << 4)) ^ ((row & 7) << 4);
        a[i] = *(const short8*)(As + row * 128 + kb);
      }
      #pragma unroll
      for (int j = 0; j < 4; ++j){
        int row = wn * 64 + j * 16 + (lane & 15);
        int kb  = (kk * 64 + ((lane >> 4) << 4)) ^ ((row & 7) << 4);
        b[j] = *(const short8*)(Bs + row * 128 + kb);
      }
      #pragma unroll
      for (int i = 0; i < 4; ++i)
        #pragma unroll
        for (int j = 0; j < 4; ++j)
          acc[i][j] = __builtin_amdgcn_mfma_f32_16x16x32_bf16(a[i], b[j], acc[i][j], 0, 0, 0);
    }
    __syncthreads();
    cur ^= 1;
  }

  const int cr = (lane >> 4) << 2;
  const int cc = lane & 15;
  #pragma unroll
  for (int i = 0; i < 4; ++i){
    #pragma unroll
    for (int j = 0; j < 4; ++j){
      int r0 = rowA0 + wm * 64 + i * 16 + cr;
      int c0 = rowB0 + wn * 64 + j * 16 + cc;
      #pragma unroll
      for (int r = 0; r < 4; ++r){
        float v = acc[i][j][r];
        if (RELU) v = fmaxf(v, 0.f);
        C[(size_t)(r0 + r) * N + c0] = f2bf(v);
      }
    }
  }
}

// ---------------------------------------------------------------------------
// rsa attention: 4 tokens, 8 heads. 256 thr = 8 batches x 32 (h,q) threads.
// ---------------------------------------------------------------------------
__global__ __launch_bounds__(256) void attn4_kernel(
    const unsigned short* __restrict__ Q, const unsigned short* __restrict__ K,
    const unsigned short* __restrict__ V, unsigned short* __restrict__ ctx)
{
  const int t = threadIdx.x;
  const int lb = t >> 5, u = t & 31, h = u >> 2, q = u & 3;
  const size_t b = (size_t)blockIdx.x * 8 + lb;
  const size_t base = b * 1024 + h * 32;

  float qf[32];
  {
    const ushort8* qp = (const ushort8*)(Q + base + q * 256);
    #pragma unroll
    for (int g = 0; g < 4; ++g){
      ushort8 v = qp[g];
      #pragma unroll
      for (int e = 0; e < 8; ++e) qf[g * 8 + e] = bf2f(v[e]);
    }
  }
  float sc[4];
  #pragma unroll
  for (int s = 0; s < 4; ++s){
    const ushort8* kp = (const ushort8*)(K + base + s * 256);
    float a0 = 0, a1 = 0, a2 = 0, a3 = 0;
    #pragma unroll
    for (int g = 0; g < 4; ++g){
      ushort8 v = kp[g];
      a0 += qf[g*8+0]*bf2f(v[0]); a1 += qf[g*8+1]*bf2f(v[1]);
      a2 += qf[g*8+2]*bf2f(v[2]); a3 += qf[g*8+3]*bf2f(v[3]);
      a0 += qf[g*8+4]*bf2f(v[4]); a1 += qf[g*8+5]*bf2f(v[5]);
      a2 += qf[g*8+6]*bf2f(v[6]); a3 += qf[g*8+7]*bf2f(v[7]);
    }
    sc[s] = ((a0 + a1) + (a2 + a3)) * 0.17677669529663687f;
  }
  float m = fmaxf(fmaxf(sc[0], sc[1]), fmaxf(sc[2], sc[3]));
  float sum = 0.f;
  #pragma unroll
  for (int s = 0; s < 4; ++s){ sc[s] = __expf(sc[s] - m); sum += sc[s]; }
  float inv = 1.f / sum;

  float o[32];
  #pragma unroll
  for (int d = 0; d < 32; ++d) o[d] = 0.f;
  #pragma unroll
  for (int s = 0; s < 4; ++s){
    float p = sc[s] * inv;
    const ushort8* vp = (const ushort8*)(V + base + s * 256);
    #pragma unroll
    for (int g = 0; g < 4; ++g){
      ushort8 v = vp[g];
      #pragma unroll
      for (int e = 0; e < 8; ++e) o[g * 8 + e] += p * bf2f(v[e]);
    }
  }
  unsigned short* cp = ctx + base + q * 256;
  #pragma unroll
  for (int g = 0; g < 4; ++g){
    ushort8 w;
    #pragma unroll
    for (int e = 0; e < 8; ++e) w[e] = f2bf(o[g * 8 + e]);
    ((ushort8*)cp)[g] = w;
  }
}

// ---------------------------------------------------------------------------
// rsa finish: refined = LN(o4 + fe); x2 = x + refined[region_id]  (bf16 out)
// ---------------------------------------------------------------------------
__global__ __launch_bounds__(256) void rsa_finish_kernel(
    const float* __restrict__ x, const unsigned short* __restrict__ o4,
    const unsigned short* __restrict__ fe, unsigned short* __restrict__ x2)
{
  const int b = blockIdx.x, d = threadIdx.x;
  const int wave = d >> 6, lane = d & 63;
  float v[4];
  #pragma unroll
  for (int r = 0; r < 4; ++r){
    size_t idx = (size_t)b * 1024 + r * 256 + d;
    v[r] = bf2f(o4[idx]) + bf2f(fe[idx]);
  }
  __shared__ float red[2][4][4];
  #pragma unroll
  for (int r = 0; r < 4; ++r){
    float s = v[r], ss = v[r] * v[r];
    #pragma unroll
    for (int off = 32; off; off >>= 1){ s += __shfl_xor(s, off); ss += __shfl_xor(ss, off); }
    if (lane == 0){ red[0][wave][r] = s; red[1][wave][r] = ss; }
  }
  __syncthreads();
  #pragma unroll
  for (int r = 0; r < 4; ++r){
    float S  = red[0][0][r] + red[0][1][r] + red[0][2][r] + red[0][3][r];
    float SS = red[1][0][r] + red[1][1][r] + red[1][2][r] + red[1][3][r];
    float mu = S * (1.f / 256.f);
    float var = SS * (1.f / 256.f) - mu * mu;
    v[r] = (v[r] - mu) * rsqrtf(var + 1e-5f);
  }
  const float* xb = x + (size_t)b * 4864 + d;
  unsigned short* xo = x2 + (size_t)b * 4864 + d;
  const int rid[19] = {0,0,1,2,3,0,3,3,0,0,0,1,2,3,0,3,3,1,2};
  #pragma unroll
  for (int c = 0; c < 19; ++c) xo[c * 256] = f2bf(xb[c * 256] + v[rid[c]]);
}

// ---------------------------------------------------------------------------
// lsa attention: 19 tokens, 8 heads. One block per batch; K,V staged in LDS.
// ---------------------------------------------------------------------------
__global__ __launch_bounds__(256) void attn19_kernel(
    const unsigned short* __restrict__ Q, const unsigned short* __restrict__ K,
    const unsigned short* __restrict__ V, unsigned short* __restrict__ ctx)
{
  __shared__ float Kl[4864];
  __shared__ float Vl[4864];
  const size_t b = blockIdx.x;
  const unsigned short* Kb = K + b * 4864;
  const unsigned short* Vb = V + b * 4864;
  for (int i = threadIdx.x; i < 4864; i += 256){ Kl[i] = bf2f(Kb[i]); Vl[i] = bf2f(Vb[i]); }
  __syncthreads();
  const int t = threadIdx.x;
  if (t >= 152) return;
  const int h = t / 19, qq = t - h * 19;

  float qf[32];
  {
    const ushort8* qp = (const ushort8*)(Q + b * 4864 + qq * 256 + h * 32);
    #pragma unroll
    for (int g = 0; g < 4; ++g){
      ushort8 v = qp[g];
      #pragma unroll
      for (int e = 0; e < 8; ++e) qf[g * 8 + e] = bf2f(v[e]);
    }
  }
  float p[19];
  float m = -1e30f;
  #pragma unroll
  for (int s = 0; s < 19; ++s){
    const float* kr = &Kl[s * 256 + h * 32];
    float a0 = 0, a1 = 0, a2 = 0, a3 = 0;
    #pragma unroll
    for (int d = 0; d < 32; d += 4){
      a0 += qf[d+0] * kr[d+0]; a1 += qf[d+1] * kr[d+1];
      a2 += qf[d+2] * kr[d+2]; a3 += qf[d+3] * kr[d+3];
    }
    p[s] = ((a0 + a1) + (a2 + a3)) * 0.17677669529663687f;
    m = fmaxf(m, p[s]);
  }
  float sum = 0.f;
  #pragma unroll
  for (int s = 0; s < 19; ++s){ p[s] = __expf(p[s] - m); sum += p[s]; }
  float inv = 1.f / sum;

  float o[32];
  #pragma unroll
  for (int d = 0; d < 32; ++d) o[d] = 0.f;
  #pragma unroll
  for (int s = 0; s < 19; ++s){
    float ps = p[s] * inv;
    const float* vr = &Vl[s * 256 + h * 32];
    #pragma unroll
    for (int d = 0; d < 32; ++d) o[d] += ps * vr[d];
  }
  unsigned short* cp = ctx + b * 4864 + qq * 256 + h * 32;
  #pragma unroll
  for (int g = 0; g < 4; ++g){
    ushort8 w;
    #pragma unroll
    for (int e = 0; e < 8; ++e) w[e] = f2bf(o[g * 8 + e]);
    ((ushort8*)cp)[g] = w;
  }
}

// ---------------------------------------------------------------------------
// out = LN(a + b) per 256-elem row; wave per row (4 rows/block).
// ---------------------------------------------------------------------------
template<int BF16OUT>
__global__ __launch_bounds__(256) void addln_kernel(
    const unsigned short* __restrict__ a, const unsigned short* __restrict__ b,
    void* __restrict__ outp)
{
  const int row = blockIdx.x * 4 + (threadIdx.x >> 6);
  const int lane = threadIdx.x & 63;
  const size_t base = (size_t)row * 256;
  ushort4v av = *(const ushort4v*)(a + base + lane * 4);
  ushort4v bv = *(const ushort4v*)(b + base + lane * 4);
  float v[4];
  #pragma unroll
  for (int i = 0; i < 4; ++i) v[i] = bf2f(av[i]) + bf2f(bv[i]);
  float s = (v[0] + v[1]) + (v[2] + v[3]);
  float ss = (v[0]*v[0] + v[1]*v[1]) + (v[2]*v[2] + v[3]*v[3]);
  #pragma unroll
  for (int off = 32; off; off >>= 1){ s += __shfl_xor(s, off); ss += __shfl_xor(ss, off); }
  float mu = s * (1.f / 256.f);
  float var = ss * (1.f / 256.f) - mu * mu;
  float rs = rsqrtf(var + 1e-5f);
  if (BF16OUT){
    ushort4v w;
    #pragma unroll
    for (int i = 0; i < 4; ++i) w[i] = f2bf((v[i] - mu) * rs);
    *(ushort4v*)((unsigned short*)outp + base + lane * 4) = w;
  } else {
    floatx4 w;
    #pragma unroll
    for (int i = 0; i < 4; ++i) w[i] = (v[i] - mu) * rs;
    *(floatx4*)((float*)outp + base + lane * 4) = w;
  }
}

// ============================================================================
extern "C" void kernel_launch(void* const* d_in, const int* in_sizes, int n_in,
                              void* d_out, int out_size, void* d_ws, size_t ws_size,
                              hipStream_t stream)
{
  (void)n_in; (void)out_size;
  const float* x  = (const float*)d_in[0];
  const float* rq = (const float*)d_in[1];
  const float* rk = (const float*)d_in[2];
  const float* rv = (const float*)d_in[3];
  const float* ro = (const float*)d_in[4];
  const float* lq = (const float*)d_in[5];
  const float* lk = (const float*)d_in[6];
  const float* lv = (const float*)d_in[7];
  const float* lo = (const float*)d_in[8];
  const float* w1 = (const float*)d_in[9];
  const float* w2 = (const float*)d_in[10];

  const int B = in_sizes[0] / 4864;          // 4096
  const int M4  = B * 4;                     // 16384
  const int M19 = B * 19;                    // 77824
  const size_t MB = 1ull << 20;
  if (ws_size < 240 * MB) return;            // need 240MB scratch

  char* ws = (char*)d_ws;
  unsigned short* WT    = (unsigned short*)(ws);             // 0..2MB
  unsigned short* FE    = (unsigned short*)(ws + 2   * MB);  // 2..10
  unsigned short* Q4    = (unsigned short*)(ws + 10  * MB);  // 10..18
  unsigned short* K4    = (unsigned short*)(ws + 18  * MB);  // 18..26
  unsigned short* V4    = (unsigned short*)(ws + 26  * MB);  // 26..34
  unsigned short* CTX4  = (unsigned short*)(ws + 34  * MB);  // 34..42
  unsigned short* O4    = (unsigned short*)(ws + 42  * MB);  // 42..50
  unsigned short* X2    = (unsigned short*)(ws + 50  * MB);  // 50..88 (38MB exact)
  unsigned short* Q19   = (unsigned short*)(ws + 88  * MB);  // 88..126
  unsigned short* K19   = (unsigned short*)(ws + 126 * MB);  // 126..164
  unsigned short* V19   = (unsigned short*)(ws + 164 * MB);  // 164..202
  unsigned short* CTX19 = (unsigned short*)(ws + 202 * MB);  // 202..240
  unsigned short* O19   = (unsigned short*)(ws + 88  * MB);  // alias Q19 (dead)
  unsigned short* FUSED = (unsigned short*)(ws + 126 * MB);  // alias K19 (dead)
  unsigned short* H     = (unsigned short*)(ws + 164 * MB);  // alias V19+CTX19 (dead), 76MB
  unsigned short* F2    = (unsigned short*)(ws + 50  * MB);  // alias X2 (dead)
  float* out = (float*)d_out;

  // 1. weights -> bf16 transposed
  wprep_all<<<4096, 256, 0, stream>>>(rq, rk, rv, ro, lq, lk, lv, lo, w1, w2, WT);
  // 2. region pool
  pool_kernel<<<B, 256, 0, stream>>>(x, FE);
  // 3. rsa QKV
  gemm_kernel<0><<<dim3(M4/128, 2), 256, 0, stream>>>(FE, WT + 0*65536, Q4, M4, 256, 256);
  gemm_kernel<0><<<dim3(M4/128, 2), 256, 0, stream>>>(FE, WT + 1*65536, K4, M4, 256, 256);
  gemm_kernel<0><<<dim3(M4/128, 2), 256, 0, stream>>>(FE, WT + 2*65536, V4, M4, 256, 256);
  // 4. rsa attention
  attn4_kernel<<<B/8, 256, 0, stream>>>(Q4, K4, V4, CTX4);
  // 5. rsa output proj
  gemm_kernel<0><<<dim3(M4/128, 2), 256, 0, stream>>>(CTX4, WT + 3*65536, O4, M4, 256, 256);
  // 6. refined = LN(o4+fe); x2 = x + refined[region_id]
  rsa_finish_kernel<<<B, 256, 0, stream>>>(x, O4, FE, X2);
  // 7. lsa QKV
  gemm_kernel<0><<<dim3(M19/128, 2), 256, 0, stream>>>(X2, WT + 4*65536, Q19, M19, 256, 256);
  gemm_kernel<0><<<dim3(M19/128, 2), 256, 0, stream>>>(X2, WT + 5*65536, K19, M19, 256, 256);
  gemm_kernel<0><<<dim3(M19/128, 2), 256, 0, stream>>>(X2, WT + 6*65536, V19, M19, 256, 256);
  // 8. lsa attention
  attn19_kernel<<<B, 256, 0, stream>>>(Q19, K19, V19, CTX19);
  // 9. lsa output proj
  gemm_kernel<0><<<dim3(M19/128, 2), 256, 0, stream>>>(CTX19, WT + 7*65536, O19, M19, 256, 256);
  // 10. fused = LN(o19 + x2)
  addln_kernel<1><<<M19/4, 256, 0, stream>>>(O19, X2, FUSED);
  // 11. FFN in two row-halves (bounds scratch for H)
  const int MH = M19 / 2;  // 38912
  for (int hf = 0; hf < 2; ++hf){
    const unsigned short* Ain = FUSED + (size_t)hf * MH * 256;
    unsigned short* F2h = F2 + (size_t)hf * MH * 256;
    gemm_kernel<1><<<dim3(MH/128, 8), 256, 0, stream>>>(Ain, WT + 524288, H, MH, 1024, 256);
    gemm_kernel<0><<<dim3(MH/128, 2), 256, 0, stream>>>(H, WT + 786432, F2h, MH, 256, 1024);
  }
  // 12. out = LN(f2 + fused)  (fp32)
  addln_kernel<0><<<M19/4, 256, 0, stream>>>(F2, FUSED, out);
}